// Round 15
// baseline (871.312 us; speedup 1.0000x reference)
//
#include <hip/hip_runtime.h>

#define NEDGES 1600000
#define NNODES 100000
#define OVCAP  (1 << 19)          // overflow record capacity (pairs)
#define NREP   8                  // per-XCD bucket replicas
#define CAPSUB 16                 // slots per sub-bucket (Poisson(4) tail ~4e-6)

typedef __bf16 bf16x8 __attribute__((ext_vector_type(8)));
typedef __bf16 bf16x4 __attribute__((ext_vector_type(4)));
typedef float f32x4 __attribute__((ext_vector_type(4)));
typedef unsigned short u16x8 __attribute__((ext_vector_type(8)));

__device__ __forceinline__ __bf16 f2bf(float f) {
  unsigned u = __builtin_bit_cast(unsigned, f);
  u += 0x7FFFu + ((u >> 16) & 1u);            // RNE round to bf16
  unsigned short s = (unsigned short)(u >> 16);
  return __builtin_bit_cast(__bf16, s);
}

// ============================================================================
// Shared helpers
// ============================================================================

__device__ __forceinline__ void cvt_row(const float* __restrict__ nodes, int t,
                                        __bf16* __restrict__ nbf) {
  float4 v0 = ((const float4*)nodes)[t * 2];
  float4 v1 = ((const float4*)nodes)[t * 2 + 1];
  bf16x8 o;
  o[0] = f2bf(v0.x); o[1] = f2bf(v0.y); o[2] = f2bf(v0.z); o[3] = f2bf(v0.w);
  o[4] = f2bf(v1.x); o[5] = f2bf(v1.y); o[6] = f2bf(v1.z); o[7] = f2bf(v1.w);
  ((bf16x8*)nbf)[t] = o;
}

__device__ __forceinline__ void weight_img(const float* __restrict__ W1,
                                           const float* __restrict__ W2,
                                           int t, __bf16* __restrict__ wimg) {
  if (t < 16384) {                       // W1 [k=128][n=128] -> [n][k] swizzled
    int k = t >> 7, n = t & 127;
    wimg[n * 128 + (((k >> 3) ^ (n & 15)) << 3) + (k & 7)] = f2bf(W1[t]);
  } else if (t < 24576) {                // W2 [k=128][n=64] -> [n][k] swizzled
    int u = t - 16384;
    int k = u >> 6, n = u & 63;
    wimg[16384 + n * 128 + (((k >> 3) ^ (n & 15)) << 3) + (k & 7)] = f2bf(W2[u]);
  }
}

// ============================================================================
// Replicated-bucket path (round-15): prep8 -> build8 -> gnn8 -> ovf.
// Mechanism: r14 counters showed build_k is line-churn-bound (WRITE 206MB for
// a 38MB payload, VALUBusy 0.4%): each rec 64B line gets ~16 random 4B stores
// from all 8 XCDs over the kernel lifetime; non-coherent per-XCD L2s bounce
// the dirty line through L3/HBM on ~every touch. Fix: 8 sub-buckets per node
// (one per replica c = blockIdx&7 ~= XCD); each 64B line (= one sub-bucket)
// is then written by ONE XCD only and retires once.
// ============================================================================

// prep8: zero replica counters (8*NNODES = 800000 = exactly one per thread),
// node->bf16 image, weight images
__global__ void prep8_k(const float* __restrict__ nodes,
                        const float* __restrict__ W1,
                        const float* __restrict__ W2,
                        unsigned* __restrict__ cntr,
                        unsigned* __restrict__ ovn,
                        __bf16* __restrict__ wimg,
                        __bf16* __restrict__ nbf) {
  const int t = blockIdx.x * 256 + threadIdx.x;   // 800000 threads
  cvt_row(nodes, t, nbf);
  weight_img(W1, W2, t, wimg);
  cntr[t] = 0u;                                   // 8 * NNODES exactly
  if (t == 0) *ovn = 0u;
}

// build8: fused convert + replica-bucketed edge scatter (2 edges/thread)
__global__ void build8_k(const float* __restrict__ nodes,
                         const int* __restrict__ edges,
                         const float* __restrict__ W1,
                         const float* __restrict__ W2,
                         unsigned* __restrict__ cntr,
                         unsigned* __restrict__ recr,
                         unsigned* __restrict__ ovf,
                         unsigned* __restrict__ ovn,
                         __bf16* __restrict__ wimg,
                         __bf16* __restrict__ nbf) {
  const int t = blockIdx.x * 256 + threadIdx.x;   // 800000 threads
  cvt_row(nodes, t, nbf);
  weight_img(W1, W2, t, wimg);
  const long cb = (long)(blockIdx.x & 7) * NNODES;  // replica base (~XCD)
  int4 e = ((const int4*)edges)[t];               // edges 2t, 2t+1
  unsigned s0 = atomicAdd(&cntr[cb + e.x], 1u);
  unsigned s1 = atomicAdd(&cntr[cb + e.y], 1u);
  unsigned s2 = atomicAdd(&cntr[cb + e.z], 1u);
  unsigned s3 = atomicAdd(&cntr[cb + e.w], 1u);
  if (s0 < CAPSUB) recr[(cb + e.x) * CAPSUB + s0] = (unsigned)e.y;
  else { unsigned q = atomicAdd(ovn, 1u);
         if (q < OVCAP) { ovf[2 * q] = (unsigned)e.x; ovf[2 * q + 1] = (unsigned)e.y; } }
  if (s1 < CAPSUB) recr[(cb + e.y) * CAPSUB + s1] = (unsigned)e.x;
  else { unsigned q = atomicAdd(ovn, 1u);
         if (q < OVCAP) { ovf[2 * q] = (unsigned)e.y; ovf[2 * q + 1] = (unsigned)e.x; } }
  if (s2 < CAPSUB) recr[(cb + e.z) * CAPSUB + s2] = (unsigned)e.w;
  else { unsigned q = atomicAdd(ovn, 1u);
         if (q < OVCAP) { ovf[2 * q] = (unsigned)e.z; ovf[2 * q + 1] = (unsigned)e.w; } }
  if (s3 < CAPSUB) recr[(cb + e.w) * CAPSUB + s3] = (unsigned)e.z;
  else { unsigned q = atomicAdd(ovn, 1u);
         if (q < OVCAP) { ovf[2 * q] = (unsigned)e.w; ovf[2 * q + 1] = (unsigned)e.z; } }
}

// overflow cleanup (expected count ~ 0; correctness-only)
__global__ void ovf_k(const float* __restrict__ nodes,
                      const float* __restrict__ W1, const float* __restrict__ b1,
                      const float* __restrict__ W2, const float* __restrict__ b2,
                      const unsigned* __restrict__ ovf,
                      const unsigned* __restrict__ ovn,
                      float* __restrict__ out) {
  unsigned n = *ovn; if (n > OVCAP) n = OVCAP;
  const unsigned total = n * 64u;
  for (unsigned idx = blockIdx.x * blockDim.x + threadIdx.x; idx < total;
       idx += gridDim.x * blockDim.x) {
    const unsigned r = idx >> 6; const int d = (int)(idx & 63u);
    const int v = (int)ovf[2 * r], u = (int)ovf[2 * r + 1];
    const float* hv = nodes + (long)v * 64;
    const float* hu = nodes + (long)u * 64;
    float md = b2[d];
    for (int h = 0; h < 128; ++h) {
      float s = b1[h];
      for (int k = 0; k < 64; ++k)
        s += hv[k] * W1[k * 128 + h] + hu[k] * W1[(64 + k) * 128 + h];
      s = s > 0.f ? s : 0.f;
      md += s * W2[h * 64 + d];
    }
    atomicAdd(out + (long)v * 64 + d, md);
  }
}

// ============================================================================
// gnn8: r10 winner with ballot-compaction preload over the 8 sub-buckets.
// Lane (s0 = lane>>4, sl = lane&15) covers sub-buckets 0-3 and 4-7 via two
// masked loads; validity from replica counts; __ballot+popcll prefix packs
// valid indices densely into LDS scratch (hid area, read back before tiles).
// Downstream tile loop byte-identical to r10. deg>64 pushed to ovf (~never).
// ============================================================================
__launch_bounds__(256, 2)
__global__ void gnn8_k(const __bf16* __restrict__ nbf,
                       const float* __restrict__ nodes,
                       const unsigned* __restrict__ cntr,
                       const unsigned* __restrict__ recr,
                       const __bf16* __restrict__ wimg,
                       const float* __restrict__ b1,
                       const float* __restrict__ b2,
                       unsigned* __restrict__ ovf,
                       unsigned* __restrict__ ovn,
                       float* __restrict__ out) {
  __shared__ __align__(16) __bf16 w1t[128 * 128];   // 32 KB [n][k] swizzled
  __shared__ __align__(16) __bf16 w2t[64 * 128];    // 16 KB [n][k] swizzled
  __shared__ __align__(16) __bf16 hid[4][16 * 128]; // 16 KB per-wave hidden

  const int tid = threadIdx.x;

  // stage W1 + W2 (pre-swizzled global images -> LDS, plain vector copies)
  {
    const u16x8* s1 = (const u16x8*)wimg;           // 2048 x 16B
    u16x8* d1 = (u16x8*)w1t;
#pragma unroll
    for (int it = 0; it < 8; ++it) d1[it * 256 + tid] = s1[it * 256 + tid];
    const u16x8* s2 = (const u16x8*)(wimg + 16384); // 1024 x 16B
    u16x8* d2 = (u16x8*)w2t;
#pragma unroll
    for (int it = 0; it < 4; ++it) d2[it * 256 + tid] = s2[it * 256 + tid];
  }
  __syncthreads();

  const int lane = tid & 63, wave = tid >> 6;
  const int col = lane & 15, quad = lane >> 4;
  __bf16* myhid = hid[wave];

  const float b2l = b2[lane];

  // XCD-bijective swizzle: 25000 % 8 == 0, chunk = 3125 blocks per XCD
  const int bid = blockIdx.x;
  const int wg = (bid & 7) * 3125 + (bid >> 3);
  const int v = wg * 4 + wave;

  // ---- replica counts (8 values, one coalesced-ish gather) ----
  unsigned cr = 0u;
  if (lane < NREP) cr = cntr[(long)lane * NNODES + v];

  // ---- sub-bucket compaction: (s0, sl) slots -> dense scratch[0..deg) ----
  const int s0 = lane >> 4, sl = lane & 15;         // sub-buckets 0-3 / 4-7
  unsigned c0 = (unsigned)__shfl((int)cr, s0, 64);
  unsigned c1 = (unsigned)__shfl((int)cr, s0 + 4, 64);
  if (c0 > CAPSUB) c0 = CAPSUB;
  if (c1 > CAPSUB) c1 = CAPSUB;
  const bool val0 = (unsigned)sl < c0;
  const bool val1 = (unsigned)sl < c1;
  unsigned i0 = 0u, i1 = 0u;
  if (val0) i0 = recr[((long)s0 * NNODES + v) * CAPSUB + sl];
  if (val1) i1 = recr[((long)(s0 + 4) * NNODES + v) * CAPSUB + sl];
  const unsigned long long m0 = __ballot(val0);
  const unsigned long long m1 = __ballot(val1);
  const unsigned long long lt = (1ull << lane) - 1ull;
  const int nb0 = __popcll(m0);
  const int degall = nb0 + __popcll(m1);
  const int deg = degall < 64 ? degall : 64;
  unsigned* scratch = (unsigned*)myhid;             // reused before tiles
  {
    const int p0 = __popcll(m0 & lt);
    if (val0) {
      if (p0 < 64) scratch[p0] = i0;
      else { unsigned q = atomicAdd(ovn, 1u);
             if (q < OVCAP) { ovf[2 * q] = (unsigned)v; ovf[2 * q + 1] = i0; } }
    }
    const int p1 = nb0 + __popcll(m1 & lt);
    if (val1) {
      if (p1 < 64) scratch[p1] = i1;
      else { unsigned q = atomicAdd(ovn, 1u);
             if (q < OVCAP) { ovf[2 * q] = (unsigned)v; ovf[2 * q + 1] = i1; } }
    }
  }
  int ridx = v;                       // owner fallback for positions >= deg
  if (lane < deg) ridx = (int)scratch[lane];

  const int ntile = (deg + 15) >> 4;

  // ---- owner half (+b1) into accv: C-init = b1 slice, then 16 MFMAs ----
  f32x4 accv[8];
  {
    const bf16x8* vrow = (const bf16x8*)(nbf + (long)v * 64);
    const bf16x8 v0f = vrow[quad];
    const bf16x8 v1f = vrow[4 + quad];
#pragma unroll
    for (int nt = 0; nt < 8; ++nt)
      accv[nt] = *(const f32x4*)&b1[nt * 16 + quad * 4];
#pragma unroll
    for (int kt = 0; kt < 2; ++kt) {
      const int kblk = kt * 4 + quad;
      const bf16x8 bx = kt ? v1f : v0f;
#pragma unroll
      for (int nt = 0; nt < 8; ++nt) {
        const int n = nt * 16 + col;
        const bf16x8 aw = *(const bf16x8*)&w1t[n * 128 + ((kblk ^ (n & 15)) << 3)];
        accv[nt] = __builtin_amdgcn_mfma_f32_16x16x32_bf16(aw, bx, accv[nt], 0, 0, 0);
      }
    }
  }

  float part[4] = {0.f, 0.f, 0.f, 0.f};

  // prologue: first tile's neighbor rows (index via register shfl)
  bf16x8 a2, a3;
  {
    const int o0n = __shfl(ridx, col, 64);
    const bf16x8* orow = (const bf16x8*)(nbf + (long)o0n * 64);
    a2 = orow[quad]; a3 = orow[4 + quad];
  }

  for (int t = 0; t < ntile; ++t) {
    const int tb = t * 16;

    // prefetch next tile's neighbor row — index is a register shfl
    const int onx = __shfl(ridx, (tb + 16 + col) & 63, 64);
    const bf16x8* prow = (const bf16x8*)(nbf + (long)onx * 64);
    const bf16x8 p2 = prow[quad];
    const bf16x8 p3 = prow[4 + quad];

    // ---- stage 1 (swapped), fused per nt: 2 MFMA -> relu -> pack -> b64 ----
#pragma unroll
    for (int nt = 0; nt < 8; ++nt) {
      const int n = nt * 16 + col;
      const bf16x8 A2 = *(const bf16x8*)&w1t[n * 128 + (((8 + quad) ^ (n & 15)) << 3)];
      const bf16x8 A3 = *(const bf16x8*)&w1t[n * 128 + (((12 + quad) ^ (n & 15)) << 3)];
      f32x4 h = __builtin_amdgcn_mfma_f32_16x16x32_bf16(A2, a2, accv[nt], 0, 0, 0);
      h = __builtin_amdgcn_mfma_f32_16x16x32_bf16(A3, a3, h, 0, 0, 0);
      bf16x4 hp;
#pragma unroll
      for (int r = 0; r < 4; ++r) {
        float x = h[r];
        hp[r] = f2bf(x > 0.0f ? x : 0.0f);
      }
      const int hblk = nt * 2 + (quad >> 1);
      *(bf16x4*)&myhid[col * 128 + ((hblk ^ col) << 3) + ((quad & 1) << 2)] = hp;
    }

    // ---- stage 2: M = hidden @ W2 (A = hid b128, B = w2t LDS) ----
    f32x4 acc2[4];
#pragma unroll
    for (int nt = 0; nt < 4; ++nt) acc2[nt] = (f32x4)0.0f;
#pragma unroll
    for (int kt = 0; kt < 4; ++kt) {
      const int kblk = kt * 4 + quad;
      const bf16x8 ah = *(const bf16x8*)&myhid[col * 128 + ((kblk ^ col) << 3)];
#pragma unroll
      for (int nt = 0; nt < 4; ++nt) {
        const int n = nt * 16 + col;
        const bf16x8 bw = *(const bf16x8*)&w2t[n * 128 + ((kblk ^ (n & 15)) << 3)];
        acc2[nt] = __builtin_amdgcn_mfma_f32_16x16x32_bf16(ah, bw, acc2[nt], 0, 0, 0);
      }
    }

    // row partials: unmasked fast path for full tiles
    if (tb + 16 <= deg) {
#pragma unroll
      for (int nt = 0; nt < 4; ++nt)
        part[nt] += (acc2[nt][0] + acc2[nt][1]) + (acc2[nt][2] + acc2[nt][3]);
    } else {
#pragma unroll
      for (int r = 0; r < 4; ++r) {
        const bool valid = (tb + quad * 4 + r) < deg;
#pragma unroll
        for (int nt = 0; nt < 4; ++nt) part[nt] += valid ? acc2[nt][r] : 0.0f;
      }
    }

    a2 = p2; a3 = p3;
  } // tiles

  // reduce across quads, select feature by quad, single coalesced store
#pragma unroll
  for (int nt = 0; nt < 4; ++nt) {
    part[nt] += __shfl_xor(part[nt], 16, 64);
    part[nt] += __shfl_xor(part[nt], 32, 64);
  }
  const float v01 = (quad & 1) ? part[1] : part[0];
  const float v23 = (quad & 1) ? part[3] : part[2];
  const float val = (quad & 2) ? v23 : v01;

  const long o = (long)v * 64 + lane;
  out[o] = nodes[o] + val + (float)deg * b2l;
}

// ============================================================================
// Direct bucket path (fallback; round-10 configuration, measured 639 us)
// ============================================================================

__global__ void zero_k(unsigned* __restrict__ cnt, unsigned* __restrict__ ovn) {
  int g = blockIdx.x * 256 + threadIdx.x;
  if (g < NNODES) cnt[g] = 0u;
  if (g == 0) *ovn = 0u;
}

__global__ void build_k(const float* __restrict__ nodes,
                        const int* __restrict__ edges,
                        const float* __restrict__ W1,
                        const float* __restrict__ W2,
                        unsigned* __restrict__ cnt,
                        unsigned* __restrict__ rec,
                        unsigned* __restrict__ ovf,
                        unsigned* __restrict__ ovn,
                        __bf16* __restrict__ wimg,
                        __bf16* __restrict__ nbf,
                        int cap) {
  const int t = blockIdx.x * 256 + threadIdx.x;   // 800000 threads
  cvt_row(nodes, t, nbf);
  weight_img(W1, W2, t, wimg);
  int4 e = ((const int4*)edges)[t];               // edges 2t, 2t+1
  unsigned s0 = atomicAdd(&cnt[e.x], 1u);
  unsigned s1 = atomicAdd(&cnt[e.y], 1u);
  unsigned s2 = atomicAdd(&cnt[e.z], 1u);
  unsigned s3 = atomicAdd(&cnt[e.w], 1u);
  if ((int)s0 < cap) rec[(long)e.x * cap + s0] = (unsigned)e.y;
  else { unsigned p = atomicAdd(ovn, 1u);
         if (p < OVCAP) { ovf[2 * p] = (unsigned)e.x; ovf[2 * p + 1] = (unsigned)e.y; } }
  if ((int)s1 < cap) rec[(long)e.y * cap + s1] = (unsigned)e.x;
  else { unsigned p = atomicAdd(ovn, 1u);
         if (p < OVCAP) { ovf[2 * p] = (unsigned)e.y; ovf[2 * p + 1] = (unsigned)e.x; } }
  if ((int)s2 < cap) rec[(long)e.z * cap + s2] = (unsigned)e.w;
  else { unsigned p = atomicAdd(ovn, 1u);
         if (p < OVCAP) { ovf[2 * p] = (unsigned)e.z; ovf[2 * p + 1] = (unsigned)e.w; } }
  if ((int)s3 < cap) rec[(long)e.w * cap + s3] = (unsigned)e.z;
  else { unsigned p = atomicAdd(ovn, 1u);
         if (p < OVCAP) { ovf[2 * p] = (unsigned)e.w; ovf[2 * p + 1] = (unsigned)e.z; } }
}

__launch_bounds__(256, 2)
__global__ void gnn_k(const __bf16* __restrict__ nbf,
                      const float* __restrict__ nodes,
                      const unsigned* __restrict__ cntoff,
                      const unsigned* __restrict__ rec,
                      const __bf16* __restrict__ wimg,
                      const float* __restrict__ b1,
                      const float* __restrict__ b2,
                      float* __restrict__ out) {
  __shared__ __align__(16) __bf16 w1t[128 * 128];
  __shared__ __align__(16) __bf16 w2t[64 * 128];
  __shared__ __align__(16) __bf16 hid[4][16 * 128];

  const int tid = threadIdx.x;
  {
    const u16x8* s1 = (const u16x8*)wimg;
    u16x8* d1 = (u16x8*)w1t;
#pragma unroll
    for (int it = 0; it < 8; ++it) d1[it * 256 + tid] = s1[it * 256 + tid];
    const u16x8* s2 = (const u16x8*)(wimg + 16384);
    u16x8* d2 = (u16x8*)w2t;
#pragma unroll
    for (int it = 0; it < 4; ++it) d2[it * 256 + tid] = s2[it * 256 + tid];
  }
  __syncthreads();

  const int lane = tid & 63, wave = tid >> 6;
  const int col = lane & 15, quad = lane >> 4;
  __bf16* myhid = hid[wave];
  const float b2l = b2[lane];

  const int bid = blockIdx.x;
  const int wg = (bid & 7) * 3125 + (bid >> 3);
  const int v = wg * 4 + wave;

  const unsigned c = cntoff[v];
  const int deg = (c < 64u) ? (int)c : 64;
  const long base = (long)v * 64;
  const int ntile = (deg + 15) >> 4;

  int ridx = v;
  if (lane < deg) ridx = (int)rec[base + lane];

  f32x4 accv[8];
  {
    const bf16x8* vrow = (const bf16x8*)(nbf + (long)v * 64);
    const bf16x8 v0f = vrow[quad];
    const bf16x8 v1f = vrow[4 + quad];
#pragma unroll
    for (int nt = 0; nt < 8; ++nt)
      accv[nt] = *(const f32x4*)&b1[nt * 16 + quad * 4];
#pragma unroll
    for (int kt = 0; kt < 2; ++kt) {
      const int kblk = kt * 4 + quad;
      const bf16x8 bx = kt ? v1f : v0f;
#pragma unroll
      for (int nt = 0; nt < 8; ++nt) {
        const int n = nt * 16 + col;
        const bf16x8 aw = *(const bf16x8*)&w1t[n * 128 + ((kblk ^ (n & 15)) << 3)];
        accv[nt] = __builtin_amdgcn_mfma_f32_16x16x32_bf16(aw, bx, accv[nt], 0, 0, 0);
      }
    }
  }

  float part[4] = {0.f, 0.f, 0.f, 0.f};

  bf16x8 a2, a3;
  {
    const int o0n = __shfl(ridx, col, 64);
    const bf16x8* orow = (const bf16x8*)(nbf + (long)o0n * 64);
    a2 = orow[quad]; a3 = orow[4 + quad];
  }

  for (int t = 0; t < ntile; ++t) {
    const int tb = t * 16;
    const int onx = __shfl(ridx, (tb + 16 + col) & 63, 64);
    const bf16x8* prow = (const bf16x8*)(nbf + (long)onx * 64);
    const bf16x8 p2 = prow[quad];
    const bf16x8 p3 = prow[4 + quad];

#pragma unroll
    for (int nt = 0; nt < 8; ++nt) {
      const int n = nt * 16 + col;
      const bf16x8 A2 = *(const bf16x8*)&w1t[n * 128 + (((8 + quad) ^ (n & 15)) << 3)];
      const bf16x8 A3 = *(const bf16x8*)&w1t[n * 128 + (((12 + quad) ^ (n & 15)) << 3)];
      f32x4 h = __builtin_amdgcn_mfma_f32_16x16x32_bf16(A2, a2, accv[nt], 0, 0, 0);
      h = __builtin_amdgcn_mfma_f32_16x16x32_bf16(A3, a3, h, 0, 0, 0);
      bf16x4 hp;
#pragma unroll
      for (int r = 0; r < 4; ++r) {
        float x = h[r];
        hp[r] = f2bf(x > 0.0f ? x : 0.0f);
      }
      const int hblk = nt * 2 + (quad >> 1);
      *(bf16x4*)&myhid[col * 128 + ((hblk ^ col) << 3) + ((quad & 1) << 2)] = hp;
    }

    f32x4 acc2[4];
#pragma unroll
    for (int nt = 0; nt < 4; ++nt) acc2[nt] = (f32x4)0.0f;
#pragma unroll
    for (int kt = 0; kt < 4; ++kt) {
      const int kblk = kt * 4 + quad;
      const bf16x8 ah = *(const bf16x8*)&myhid[col * 128 + ((kblk ^ col) << 3)];
#pragma unroll
      for (int nt = 0; nt < 4; ++nt) {
        const int n = nt * 16 + col;
        const bf16x8 bw = *(const bf16x8*)&w2t[n * 128 + ((kblk ^ (n & 15)) << 3)];
        acc2[nt] = __builtin_amdgcn_mfma_f32_16x16x32_bf16(ah, bw, acc2[nt], 0, 0, 0);
      }
    }

    if (tb + 16 <= deg) {
#pragma unroll
      for (int nt = 0; nt < 4; ++nt)
        part[nt] += (acc2[nt][0] + acc2[nt][1]) + (acc2[nt][2] + acc2[nt][3]);
    } else {
#pragma unroll
      for (int r = 0; r < 4; ++r) {
        const bool valid = (tb + quad * 4 + r) < deg;
#pragma unroll
        for (int nt = 0; nt < 4; ++nt) part[nt] += valid ? acc2[nt][r] : 0.0f;
      }
    }

    a2 = p2; a3 = p3;
  }

#pragma unroll
  for (int nt = 0; nt < 4; ++nt) {
    part[nt] += __shfl_xor(part[nt], 16, 64);
    part[nt] += __shfl_xor(part[nt], 32, 64);
  }
  const float v01 = (quad & 1) ? part[1] : part[0];
  const float v23 = (quad & 1) ? part[3] : part[2];
  const float val = (quad & 2) ? v23 : v01;

  const long o = (long)v * 64 + lane;
  out[o] = nodes[o] + val + (float)deg * b2l;
}

// ============================================================================
// Last-resort fallback: round-0 atomic-scatter kernel
// ============================================================================

__global__ void init_out(const float* __restrict__ nodes, float* __restrict__ out) {
  int i = blockIdx.x * blockDim.x + threadIdx.x;
  ((float4*)out)[i] = ((const float4*)nodes)[i];
}

__launch_bounds__(256, 2)
__global__ void edge_mlp(const float* __restrict__ nodes,
                         const int* __restrict__ edges,
                         const float* __restrict__ W1,
                         const float* __restrict__ b1,
                         const float* __restrict__ W2,
                         const float* __restrict__ b2,
                         float* __restrict__ out) {
  __shared__ __bf16 w1t[128 * 128];
  __shared__ __bf16 w2t[64 * 128];
  __shared__ __bf16 hid[4][16 * 128];

  const int tid = threadIdx.x;

  for (int it = 0; it < 16; ++it) {
    int q = it * 256 + tid;
    int k = q >> 5;
    int nc = (q & 31) << 2;
    float4 v = ((const float4*)W1)[q];
    float vv[4] = {v.x, v.y, v.z, v.w};
#pragma unroll
    for (int c = 0; c < 4; ++c) {
      int n = nc + c;
      int blk = (k >> 3) ^ (n & 15);
      w1t[n * 128 + blk * 8 + (k & 7)] = f2bf(vv[c]);
    }
  }
  for (int it = 0; it < 8; ++it) {
    int q = it * 256 + tid;
    int k = q >> 4;
    int nc = (q & 15) << 2;
    float4 v = ((const float4*)W2)[q];
    float vv[4] = {v.x, v.y, v.z, v.w};
#pragma unroll
    for (int c = 0; c < 4; ++c) {
      int n = nc + c;
      int blk = (k >> 3) ^ (n & 15);
      w2t[n * 128 + blk * 8 + (k & 7)] = f2bf(vv[c]);
    }
  }
  __syncthreads();

  const int lane = tid & 63;
  const int wave = tid >> 6;
  const int col = lane & 15;
  const int quad = lane >> 4;
  __bf16* myhid = hid[wave];

  float b1v[8], b2v[4];
#pragma unroll
  for (int nt = 0; nt < 8; ++nt) b1v[nt] = b1[nt * 16 + col];
#pragma unroll
  for (int nt = 0; nt < 4; ++nt) b2v[nt] = b2[nt * 16 + col];

  for (int t = 0; t < 8; ++t) {
    const int e0 = blockIdx.x * 512 + wave * 128 + t * 16;
    const int e = e0 + col;
    const int ie = edges[2 * e];
    const int je = edges[2 * e + 1];

    bf16x8 af[4];
#pragma unroll
    for (int kt = 0; kt < 4; ++kt) {
      int k = kt * 32 + quad * 8;
      const float* src = (k < 64) ? (nodes + (long)ie * 64 + k)
                                  : (nodes + (long)je * 64 + (k - 64));
      float4 v0 = ((const float4*)src)[0];
      float4 v1 = ((const float4*)src)[1];
      bf16x8 a;
      a[0] = f2bf(v0.x); a[1] = f2bf(v0.y); a[2] = f2bf(v0.z); a[3] = f2bf(v0.w);
      a[4] = f2bf(v1.x); a[5] = f2bf(v1.y); a[6] = f2bf(v1.z); a[7] = f2bf(v1.w);
      af[kt] = a;
    }

#pragma unroll
    for (int dir = 0; dir < 2; ++dir) {
      f32x4 acc[8];
#pragma unroll
      for (int nt = 0; nt < 8; ++nt) acc[nt] = (f32x4)0.0f;
#pragma unroll
      for (int kt = 0; kt < 4; ++kt) {
        int kblk = kt * 4 + quad;
        if (dir) kblk ^= 8;
#pragma unroll
        for (int nt = 0; nt < 8; ++nt) {
          int n = nt * 16 + col;
          const bf16x8 bf = *(const bf16x8*)&w1t[n * 128 + ((kblk ^ (n & 15)) << 3)];
          acc[nt] = __builtin_amdgcn_mfma_f32_16x16x32_bf16(af[kt], bf, acc[nt], 0, 0, 0);
        }
      }
#pragma unroll
      for (int nt = 0; nt < 8; ++nt) {
        int unit = nt * 16 + col;
#pragma unroll
        for (int r = 0; r < 4; ++r) {
          int m = quad * 4 + r;
          float h = acc[nt][r] + b1v[nt];
          h = h > 0.0f ? h : 0.0f;
          myhid[m * 128 + (((unit >> 3) ^ m) << 3) + (unit & 7)] = f2bf(h);
        }
      }

      f32x4 acc2[4];
#pragma unroll
      for (int nt = 0; nt < 4; ++nt) acc2[nt] = (f32x4)0.0f;
#pragma unroll
      for (int kt = 0; kt < 4; ++kt) {
        int kblk = kt * 4 + quad;
        const bf16x8 ah = *(const bf16x8*)&myhid[col * 128 + ((kblk ^ col) << 3)];
#pragma unroll
        for (int nt = 0; nt < 4; ++nt) {
          int n = nt * 16 + col;
          const bf16x8 bf = *(const bf16x8*)&w2t[n * 128 + ((kblk ^ (n & 15)) << 3)];
          acc2[nt] = __builtin_amdgcn_mfma_f32_16x16x32_bf16(ah, bf, acc2[nt], 0, 0, 0);
        }
      }

#pragma unroll
      for (int r = 0; r < 4; ++r) {
        int em = quad * 4 + r;
        int node = __shfl(dir == 0 ? ie : je, em, 64);
        float* dst = out + (long)node * 64;
#pragma unroll
        for (int nt = 0; nt < 4; ++nt) {
          atomicAdd(dst + nt * 16 + col, acc2[nt][r] + b2v[nt]);
        }
      }
    }
  }
}

// ============================================================================

extern "C" void kernel_launch(void* const* d_in, const int* in_sizes, int n_in,
                              void* d_out, int out_size, void* d_ws, size_t ws_size,
                              hipStream_t stream) {
  const float* nodes = (const float*)d_in[0];
  const int*   edges = (const int*)d_in[1];
  const float* W1    = (const float*)d_in[2];
  const float* b1    = (const float*)d_in[3];
  const float* W2    = (const float*)d_in[4];
  const float* b2    = (const float*)d_in[5];
  float* out = (float*)d_out;

  char* w = (char*)d_ws;
  auto al = [](size_t x) { return (x + 255) & ~(size_t)255; };

  const int CAP = 64;

  // ---- replicated-bucket layout ----
  size_t o = 0;
  unsigned* cntr = (unsigned*)(w + o); o = al(o + (size_t)NREP * NNODES * 4);
  unsigned* ovn  = (unsigned*)(w + o); o = al(o + 256);
  __bf16* wimg   = (__bf16*)(w + o);   o = al(o + (size_t)24576 * 2);
  __bf16* nbf    = (__bf16*)(w + o);   o = al(o + (size_t)NNODES * 64 * 2);
  unsigned* ovf  = (unsigned*)(w + o); o = al(o + (size_t)OVCAP * 2 * 4);
  unsigned* recr = (unsigned*)(w + o);
  const size_t need_rep = o + (size_t)NREP * NNODES * CAPSUB * 4;

  // ---- direct-bucket layout (fallback; r10) ----
  size_t d = 0;
  unsigned* cnt  = (unsigned*)(w + d); d = al(d + (size_t)NNODES * 4);
  unsigned* ovn2 = (unsigned*)(w + d); d = al(d + 256);
  __bf16* wimg2  = (__bf16*)(w + d);   d = al(d + (size_t)24576 * 2);
  __bf16* nbf2   = (__bf16*)(w + d);   d = al(d + (size_t)NNODES * 64 * 2);
  unsigned* ovf2 = (unsigned*)(w + d); d = al(d + (size_t)OVCAP * 2 * 4);
  unsigned* rec2 = (unsigned*)(w + d);
  const size_t need_bucket = d + (size_t)NNODES * CAP * 4;

  if (d_ws && ws_size >= need_rep) {
    prep8_k<<<3125, 256, 0, stream>>>(nodes, W1, W2, cntr, ovn, wimg, nbf);
    build8_k<<<3125, 256, 0, stream>>>(nodes, edges, W1, W2, cntr, recr,
                                       ovf, ovn, wimg, nbf);
    gnn8_k<<<25000, 256, 0, stream>>>(nbf, nodes, cntr, recr, wimg, b1, b2,
                                      ovf, ovn, out);
    ovf_k<<<104, 256, 0, stream>>>(nodes, W1, b1, W2, b2, ovf, ovn, out);
  } else if (d_ws && ws_size >= need_bucket) {
    zero_k<<<391, 256, 0, stream>>>(cnt, ovn2);
    build_k<<<3125, 256, 0, stream>>>(nodes, edges, W1, W2, cnt, rec2, ovf2,
                                      ovn2, wimg2, nbf2, CAP);
    gnn_k<<<25000, 256, 0, stream>>>(nbf2, nodes, cnt, rec2, wimg2, b1, b2, out);
    ovf_k<<<104, 256, 0, stream>>>(nodes, W1, b1, W2, b2, ovf2, ovn2, out);
  } else {
    init_out<<<6250, 256, 0, stream>>>(nodes, out);
    edge_mlp<<<3125, 256, 0, stream>>>(nodes, edges, W1, b1, W2, b2, out);
  }
}

// Round 16
// 634.654 us; speedup vs baseline: 1.3729x; 1.3729x over previous
//
#include <hip/hip_runtime.h>

#define NEDGES 1600000
#define NNODES 100000
#define OVCAP  (1 << 19)          // overflow record capacity (pairs)

typedef __bf16 bf16x8 __attribute__((ext_vector_type(8)));
typedef __bf16 bf16x4 __attribute__((ext_vector_type(4)));
typedef float f32x4 __attribute__((ext_vector_type(4)));
typedef unsigned short u16x8 __attribute__((ext_vector_type(8)));

__device__ __forceinline__ __bf16 f2bf(float f) {
  unsigned u = __builtin_bit_cast(unsigned, f);
  u += 0x7FFFu + ((u >> 16) & 1u);            // RNE round to bf16
  unsigned short s = (unsigned short)(u >> 16);
  return __builtin_bit_cast(__bf16, s);
}

// ============================================================================
// Shared helpers
// ============================================================================

__device__ __forceinline__ void cvt_row(const float* __restrict__ nodes, int t,
                                        __bf16* __restrict__ nbf) {
  float4 v0 = ((const float4*)nodes)[t * 2];
  float4 v1 = ((const float4*)nodes)[t * 2 + 1];
  bf16x8 o;
  o[0] = f2bf(v0.x); o[1] = f2bf(v0.y); o[2] = f2bf(v0.z); o[3] = f2bf(v0.w);
  o[4] = f2bf(v1.x); o[5] = f2bf(v1.y); o[6] = f2bf(v1.z); o[7] = f2bf(v1.w);
  ((bf16x8*)nbf)[t] = o;
}

__device__ __forceinline__ void weight_img(const float* __restrict__ W1,
                                           const float* __restrict__ W2,
                                           int t, __bf16* __restrict__ wimg) {
  if (t < 16384) {                       // W1 [k=128][n=128] -> [n][k] swizzled
    int k = t >> 7, n = t & 127;
    wimg[n * 128 + (((k >> 3) ^ (n & 15)) << 3) + (k & 7)] = f2bf(W1[t]);
  } else if (t < 24576) {                // W2 [k=128][n=64] -> [n][k] swizzled
    int u = t - 16384;
    int k = u >> 6, n = u & 63;
    wimg[16384 + n * 128 + (((k >> 3) ^ (n & 15)) << 3) + (k & 7)] = f2bf(W2[u]);
  }
}

// ============================================================================
// Bucket path: zero -> build(fused) -> gnn -> ovf
// FINAL CONFIGURATION (round-10/14, measured 639 us total; 17% under the
// 772 us session baseline). Build-scheme scoreboard (all measured):
//   direct node-bucket scatter (this) ........ 312 us
//   lean 1-edge/thread split (r12) ........... ~335 us
//   nontemporal rec stores (r4) .............. neutral
//   two-level partition+LDS bucketing (r13) .. 738 us (atomic serialization)
//   8x XCD-replicated sub-buckets (r15) ...... ~480 us (2x line footprint)
// gnn levers exhausted: occupancy register-tier-capped (r7/r9/r11), rec-load
// chain removed via whole-bucket preload (r10), LDS/W2 placement tuned
// (r11/r12), sub-bucket compaction regresses (r15).
// ============================================================================

__global__ void zero_k(unsigned* __restrict__ cnt, unsigned* __restrict__ ovn) {
  int g = blockIdx.x * 256 + threadIdx.x;
  if (g < NNODES) cnt[g] = 0u;
  if (g == 0) *ovn = 0u;
}

// fused: node->bf16 convert, weight images, edge bucketing (2 edges/thread)
__global__ void build_k(const float* __restrict__ nodes,
                        const int* __restrict__ edges,
                        const float* __restrict__ W1,
                        const float* __restrict__ W2,
                        unsigned* __restrict__ cnt,
                        unsigned* __restrict__ rec,
                        unsigned* __restrict__ ovf,
                        unsigned* __restrict__ ovn,
                        __bf16* __restrict__ wimg,
                        __bf16* __restrict__ nbf,
                        int cap) {
  const int t = blockIdx.x * 256 + threadIdx.x;   // 800000 threads
  cvt_row(nodes, t, nbf);
  weight_img(W1, W2, t, wimg);
  int4 e = ((const int4*)edges)[t];               // edges 2t, 2t+1
  // issue all four returning atomics first (ILP), then the dependent stores
  unsigned s0 = atomicAdd(&cnt[e.x], 1u);
  unsigned s1 = atomicAdd(&cnt[e.y], 1u);
  unsigned s2 = atomicAdd(&cnt[e.z], 1u);
  unsigned s3 = atomicAdd(&cnt[e.w], 1u);
  if ((int)s0 < cap) rec[(long)e.x * cap + s0] = (unsigned)e.y;
  else { unsigned p = atomicAdd(ovn, 1u);
         if (p < OVCAP) { ovf[2 * p] = (unsigned)e.x; ovf[2 * p + 1] = (unsigned)e.y; } }
  if ((int)s1 < cap) rec[(long)e.y * cap + s1] = (unsigned)e.x;
  else { unsigned p = atomicAdd(ovn, 1u);
         if (p < OVCAP) { ovf[2 * p] = (unsigned)e.y; ovf[2 * p + 1] = (unsigned)e.x; } }
  if ((int)s2 < cap) rec[(long)e.z * cap + s2] = (unsigned)e.w;
  else { unsigned p = atomicAdd(ovn, 1u);
         if (p < OVCAP) { ovf[2 * p] = (unsigned)e.z; ovf[2 * p + 1] = (unsigned)e.w; } }
  if ((int)s3 < cap) rec[(long)e.w * cap + s3] = (unsigned)e.z;
  else { unsigned p = atomicAdd(ovn, 1u);
         if (p < OVCAP) { ovf[2 * p] = (unsigned)e.w; ovf[2 * p + 1] = (unsigned)e.z; } }
}

// overflow cleanup (expected count = 0 for this input; correctness-only)
__global__ void ovf_k(const float* __restrict__ nodes,
                      const float* __restrict__ W1, const float* __restrict__ b1,
                      const float* __restrict__ W2, const float* __restrict__ b2,
                      const unsigned* __restrict__ ovf,
                      const unsigned* __restrict__ ovn,
                      float* __restrict__ out) {
  unsigned n = *ovn; if (n > OVCAP) n = OVCAP;
  const unsigned total = n * 64u;
  for (unsigned idx = blockIdx.x * blockDim.x + threadIdx.x; idx < total;
       idx += gridDim.x * blockDim.x) {
    const unsigned r = idx >> 6; const int d = (int)(idx & 63u);
    const int v = (int)ovf[2 * r], u = (int)ovf[2 * r + 1];
    const float* hv = nodes + (long)v * 64;
    const float* hu = nodes + (long)u * 64;
    float md = b2[d];
    for (int h = 0; h < 128; ++h) {
      float s = b1[h];
      for (int k = 0; k < 64; ++k)
        s += hv[k] * W1[k * 128 + h] + hu[k] * W1[(64 + k) * 128 + h];
      s = s > 0.f ? s : 0.f;
      md += s * W2[h * 64 + d];
    }
    atomicAdd(out + (long)v * 64 + d, md);
  }
}

// ============================================================================
// Bucket-mode gather GNN kernel — ROUND-10 WINNER, byte-identical.
// ONE NODE PER WAVE, 256 threads, w1t+w2t+hid[4] = 64 KB LDS, grid 25000 +
// XCD swizzle, VGPR 116 (+~64 acc regs -> 129-256 tier -> 8 waves/CU; hard
// register-tier cap). Whole-bucket index preload (one coalesced rec load;
// per-tile indices via register shfl) + 1-tile-ahead row prefetch.
// ============================================================================
__launch_bounds__(256, 2)
__global__ void gnn_k(const __bf16* __restrict__ nbf,
                      const float* __restrict__ nodes,
                      const unsigned* __restrict__ cntoff,
                      const unsigned* __restrict__ rec,
                      const __bf16* __restrict__ wimg,
                      const float* __restrict__ b1,
                      const float* __restrict__ b2,
                      float* __restrict__ out) {
  __shared__ __align__(16) __bf16 w1t[128 * 128];   // 32 KB [n][k] swizzled
  __shared__ __align__(16) __bf16 w2t[64 * 128];    // 16 KB [n][k] swizzled
  __shared__ __align__(16) __bf16 hid[4][16 * 128]; // 16 KB per-wave hidden

  const int tid = threadIdx.x;

  // stage W1 + W2 (pre-swizzled global images -> LDS, plain vector copies)
  {
    const u16x8* s1 = (const u16x8*)wimg;           // 2048 x 16B
    u16x8* d1 = (u16x8*)w1t;
#pragma unroll
    for (int it = 0; it < 8; ++it) d1[it * 256 + tid] = s1[it * 256 + tid];
    const u16x8* s2 = (const u16x8*)(wimg + 16384); // 1024 x 16B
    u16x8* d2 = (u16x8*)w2t;
#pragma unroll
    for (int it = 0; it < 4; ++it) d2[it * 256 + tid] = s2[it * 256 + tid];
  }
  __syncthreads();

  const int lane = tid & 63, wave = tid >> 6;
  const int col = lane & 15, quad = lane >> 4;
  __bf16* myhid = hid[wave];

  const float b2l = b2[lane];

  // XCD-bijective swizzle: 25000 % 8 == 0, chunk = 3125 blocks per XCD
  const int bid = blockIdx.x;
  const int wg = (bid & 7) * 3125 + (bid >> 3);
  const int v = wg * 4 + wave;

  const unsigned c = cntoff[v];
  const int deg = (c < 64u) ? (int)c : 64;
  const long base = (long)v * 64;
  const int ntile = (deg + 15) >> 4;

  // ---- whole-bucket record preload: one coalesced load, one index/lane ----
  int ridx = v;                       // owner fallback for positions >= deg
  if (lane < deg) ridx = (int)rec[base + lane];

  // ---- owner half (+b1) into accv: C-init = b1 slice, then 16 MFMAs ----
  // B-frag (owner row) is lane-broadcast per quad: h_v[k], all m identical.
  f32x4 accv[8];
  {
    const bf16x8* vrow = (const bf16x8*)(nbf + (long)v * 64);
    const bf16x8 v0f = vrow[quad];
    const bf16x8 v1f = vrow[4 + quad];
#pragma unroll
    for (int nt = 0; nt < 8; ++nt)
      accv[nt] = *(const f32x4*)&b1[nt * 16 + quad * 4];
#pragma unroll
    for (int kt = 0; kt < 2; ++kt) {
      const int kblk = kt * 4 + quad;
      const bf16x8 bx = kt ? v1f : v0f;
#pragma unroll
      for (int nt = 0; nt < 8; ++nt) {
        const int n = nt * 16 + col;
        const bf16x8 aw = *(const bf16x8*)&w1t[n * 128 + ((kblk ^ (n & 15)) << 3)];
        accv[nt] = __builtin_amdgcn_mfma_f32_16x16x32_bf16(aw, bx, accv[nt], 0, 0, 0);
      }
    }
  }

  float part[4] = {0.f, 0.f, 0.f, 0.f};

  // prologue: first tile's neighbor rows (index from shfl of preloaded bucket)
  bf16x8 a2, a3;
  {
    const int o0n = __shfl(ridx, col, 64);
    const bf16x8* orow = (const bf16x8*)(nbf + (long)o0n * 64);
    a2 = orow[quad]; a3 = orow[4 + quad];
  }

  for (int t = 0; t < ntile; ++t) {
    const int tb = t * 16;

    // prefetch next tile's neighbor row — index is a register shfl, so the
    // gather issues immediately (no rec-load dependency). Last iteration
    // wraps ((tb+16+col)&63) and fetches a harmless already-cached row.
    const int onx = __shfl(ridx, (tb + 16 + col) & 63, 64);
    const bf16x8* prow = (const bf16x8*)(nbf + (long)onx * 64);
    const bf16x8 p2 = prow[quad];
    const bf16x8 p3 = prow[4 + quad];

    // ---- stage 1 (swapped), fused per nt: 2 MFMA -> relu -> pack -> b64 ----
#pragma unroll
    for (int nt = 0; nt < 8; ++nt) {
      const int n = nt * 16 + col;
      const bf16x8 A2 = *(const bf16x8*)&w1t[n * 128 + (((8 + quad) ^ (n & 15)) << 3)];
      const bf16x8 A3 = *(const bf16x8*)&w1t[n * 128 + (((12 + quad) ^ (n & 15)) << 3)];
      f32x4 h = __builtin_amdgcn_mfma_f32_16x16x32_bf16(A2, a2, accv[nt], 0, 0, 0);
      h = __builtin_amdgcn_mfma_f32_16x16x32_bf16(A3, a3, h, 0, 0, 0);
      bf16x4 hp;
#pragma unroll
      for (int r = 0; r < 4; ++r) {
        float x = h[r];
        hp[r] = f2bf(x > 0.0f ? x : 0.0f);
      }
      const int hblk = nt * 2 + (quad >> 1);
      *(bf16x4*)&myhid[col * 128 + ((hblk ^ col) << 3) + ((quad & 1) << 2)] = hp;
    }

    // ---- stage 2: M = hidden @ W2 (A = hid b128, B = w2t LDS) ----
    f32x4 acc2[4];
#pragma unroll
    for (int nt = 0; nt < 4; ++nt) acc2[nt] = (f32x4)0.0f;
#pragma unroll
    for (int kt = 0; kt < 4; ++kt) {
      const int kblk = kt * 4 + quad;
      const bf16x8 ah = *(const bf16x8*)&myhid[col * 128 + ((kblk ^ col) << 3)];
#pragma unroll
      for (int nt = 0; nt < 4; ++nt) {
        const int n = nt * 16 + col;
        const bf16x8 bw = *(const bf16x8*)&w2t[n * 128 + ((kblk ^ (n & 15)) << 3)];
        acc2[nt] = __builtin_amdgcn_mfma_f32_16x16x32_bf16(ah, bw, acc2[nt], 0, 0, 0);
      }
    }

    // row partials: unmasked fast path for full tiles
    if (tb + 16 <= deg) {
#pragma unroll
      for (int nt = 0; nt < 4; ++nt)
        part[nt] += (acc2[nt][0] + acc2[nt][1]) + (acc2[nt][2] + acc2[nt][3]);
    } else {
#pragma unroll
      for (int r = 0; r < 4; ++r) {
        const bool valid = (tb + quad * 4 + r) < deg;
#pragma unroll
        for (int nt = 0; nt < 4; ++nt) part[nt] += valid ? acc2[nt][r] : 0.0f;
      }
    }

    a2 = p2; a3 = p3;
  } // tiles

  // reduce across quads, select feature by quad, single coalesced store
#pragma unroll
  for (int nt = 0; nt < 4; ++nt) {
    part[nt] += __shfl_xor(part[nt], 16, 64);
    part[nt] += __shfl_xor(part[nt], 32, 64);
  }
  const float v01 = (quad & 1) ? part[1] : part[0];
  const float v23 = (quad & 1) ? part[3] : part[2];
  const float val = (quad & 2) ? v23 : v01;

  const long o = (long)v * 64 + lane;
  out[o] = nodes[o] + val + (float)deg * b2l;
}

// ============================================================================
// CSR-mode gather GNN kernel (fallback only)
// ============================================================================
__launch_bounds__(256, 2)
__global__ void gnn_csr_k(const __bf16* __restrict__ nbf,
                          const float* __restrict__ nodes,
                          const unsigned* __restrict__ off,
                          const unsigned* __restrict__ rec,
                          const __bf16* __restrict__ wimg,
                          const float* __restrict__ b1,
                          const float* __restrict__ b2,
                          float* __restrict__ out) {
  __shared__ __align__(16) __bf16 w1t[128 * 128];
  __shared__ __align__(16) __bf16 w2t[64 * 128];
  __shared__ __align__(16) __bf16 hid[4][16 * 128];

  const int tid = threadIdx.x;
  {
    const u16x8* s1 = (const u16x8*)wimg;
    u16x8* d1 = (u16x8*)w1t;
#pragma unroll
    for (int it = 0; it < 8; ++it) d1[it * 256 + tid] = s1[it * 256 + tid];
    const u16x8* s2 = (const u16x8*)(wimg + 16384);
    u16x8* d2 = (u16x8*)w2t;
#pragma unroll
    for (int it = 0; it < 4; ++it) d2[it * 256 + tid] = s2[it * 256 + tid];
  }
  __syncthreads();

  const int lane = tid & 63, wave = tid >> 6;
  const int col = lane & 15, quad = lane >> 4;
  __bf16* myhid = hid[wave];
  const float b2l = b2[lane];

  const int bid = blockIdx.x;
  const int wg = (bid & 7) * 3125 + (bid >> 3);
  const int v = wg * 4 + wave;

  const unsigned o0 = off[v];
  const int deg = (int)(off[v + 1] - o0);
  const long base = (long)o0;
  const int ntile = (deg + 15) >> 4;

  f32x4 accv[8];
  {
    const bf16x8* vrow = (const bf16x8*)(nbf + (long)v * 64);
    const bf16x8 v0f = vrow[quad];
    const bf16x8 v1f = vrow[4 + quad];
#pragma unroll
    for (int nt = 0; nt < 8; ++nt)
      accv[nt] = *(const f32x4*)&b1[nt * 16 + quad * 4];
#pragma unroll
    for (int kt = 0; kt < 2; ++kt) {
      const int kblk = kt * 4 + quad;
      const bf16x8 bx = kt ? v1f : v0f;
#pragma unroll
      for (int nt = 0; nt < 8; ++nt) {
        const int n = nt * 16 + col;
        const bf16x8 aw = *(const bf16x8*)&w1t[n * 128 + ((kblk ^ (n & 15)) << 3)];
        accv[nt] = __builtin_amdgcn_mfma_f32_16x16x32_bf16(aw, bx, accv[nt], 0, 0, 0);
      }
    }
  }

  float part[4] = {0.f, 0.f, 0.f, 0.f};

  bf16x8 a2, a3;
  {
    int o0n = v;
    if (col < deg) o0n = (int)rec[base + col];
    const bf16x8* orow = (const bf16x8*)(nbf + (long)o0n * 64);
    a2 = orow[quad]; a3 = orow[4 + quad];
  }

  for (int t = 0; t < ntile; ++t) {
    const int tb = t * 16;
    int onx = v;
    {
      const int rr = tb + 16 + col;
      if (rr < deg) onx = (int)rec[base + rr];
    }
    const bf16x8* prow = (const bf16x8*)(nbf + (long)onx * 64);
    const bf16x8 p2 = prow[quad];
    const bf16x8 p3 = prow[4 + quad];

#pragma unroll
    for (int nt = 0; nt < 8; ++nt) {
      const int n = nt * 16 + col;
      const bf16x8 A2 = *(const bf16x8*)&w1t[n * 128 + (((8 + quad) ^ (n & 15)) << 3)];
      const bf16x8 A3 = *(const bf16x8*)&w1t[n * 128 + (((12 + quad) ^ (n & 15)) << 3)];
      f32x4 h = __builtin_amdgcn_mfma_f32_16x16x32_bf16(A2, a2, accv[nt], 0, 0, 0);
      h = __builtin_amdgcn_mfma_f32_16x16x32_bf16(A3, a3, h, 0, 0, 0);
      bf16x4 hp;
#pragma unroll
      for (int r = 0; r < 4; ++r) {
        float x = h[r];
        hp[r] = f2bf(x > 0.0f ? x : 0.0f);
      }
      const int hblk = nt * 2 + (quad >> 1);
      *(bf16x4*)&myhid[col * 128 + ((hblk ^ col) << 3) + ((quad & 1) << 2)] = hp;
    }

    f32x4 acc2[4];
#pragma unroll
    for (int nt = 0; nt < 4; ++nt) acc2[nt] = (f32x4)0.0f;
#pragma unroll
    for (int kt = 0; kt < 4; ++kt) {
      const int kblk = kt * 4 + quad;
      const bf16x8 ah = *(const bf16x8*)&myhid[col * 128 + ((kblk ^ col) << 3)];
#pragma unroll
      for (int nt = 0; nt < 4; ++nt) {
        const int n = nt * 16 + col;
        const bf16x8 bw = *(const bf16x8*)&w2t[n * 128 + ((kblk ^ (n & 15)) << 3)];
        acc2[nt] = __builtin_amdgcn_mfma_f32_16x16x32_bf16(ah, bw, acc2[nt], 0, 0, 0);
      }
    }

    if (tb + 16 <= deg) {
#pragma unroll
      for (int nt = 0; nt < 4; ++nt)
        part[nt] += (acc2[nt][0] + acc2[nt][1]) + (acc2[nt][2] + acc2[nt][3]);
    } else {
#pragma unroll
      for (int r = 0; r < 4; ++r) {
        const bool valid = (tb + quad * 4 + r) < deg;
#pragma unroll
        for (int nt = 0; nt < 4; ++nt) part[nt] += valid ? acc2[nt][r] : 0.0f;
      }
    }

    a2 = p2; a3 = p3;
  }

#pragma unroll
  for (int nt = 0; nt < 4; ++nt) {
    part[nt] += __shfl_xor(part[nt], 16, 64);
    part[nt] += __shfl_xor(part[nt], 32, 64);
  }
  const float v01 = (quad & 1) ? part[1] : part[0];
  const float v23 = (quad & 1) ? part[3] : part[2];
  const float val = (quad & 2) ? v23 : v01;

  const long o = (long)v * 64 + lane;
  out[o] = nodes[o] + val + (float)deg * b2l;
}

// ============================================================================
// CSR fallback build (multi-block scan)
// ============================================================================

__global__ void prep_k(const float* __restrict__ nodes,
                       const float* __restrict__ W1,
                       const float* __restrict__ W2,
                       unsigned* __restrict__ cnt,
                       __bf16* __restrict__ wimg,
                       __bf16* __restrict__ nbf) {
  const int t = blockIdx.x * 256 + threadIdx.x;
  cvt_row(nodes, t, nbf);
  if (t < NNODES) cnt[t] = 0u;
  weight_img(W1, W2, t, wimg);
}

__global__ void hist_k(const int* __restrict__ edges, unsigned* __restrict__ cnt) {
  const int t = blockIdx.x * 256 + threadIdx.x;
  int4 e = ((const int4*)edges)[t];
  atomicAdd(&cnt[e.x], 1u); atomicAdd(&cnt[e.y], 1u);
  atomicAdd(&cnt[e.z], 1u); atomicAdd(&cnt[e.w], 1u);
}

__global__ void scanA_k(const unsigned* __restrict__ cnt, unsigned* __restrict__ bsum) {
  __shared__ unsigned s[1024];
  const int tid = threadIdx.x;
  const int g = blockIdx.x * 1024 + tid;
  s[tid] = (g < NNODES) ? cnt[g] : 0u;
  __syncthreads();
  for (int d = 512; d > 0; d >>= 1) {
    if (tid < d) s[tid] += s[tid + d];
    __syncthreads();
  }
  if (tid == 0) bsum[blockIdx.x] = s[0];
}

__global__ void scanB_k(const unsigned* __restrict__ cnt,
                        const unsigned* __restrict__ bsum,
                        unsigned* __restrict__ off, unsigned* __restrict__ cur) {
  __shared__ unsigned s[1024];
  const int tid = threadIdx.x;
  const int b = blockIdx.x;
  const int g = b * 1024 + tid;
  unsigned pfx = 0;
  for (int j = 0; j < b; ++j) pfx += bsum[j];
  const unsigned x = (g < NNODES) ? cnt[g] : 0u;
  s[tid] = x;
  __syncthreads();
  for (int d = 1; d < 1024; d <<= 1) {
    unsigned tv = (tid >= d) ? s[tid - d] : 0u;
    __syncthreads();
    s[tid] += tv;
    __syncthreads();
  }
  const unsigned excl = pfx + s[tid] - x;
  if (g < NNODES) { off[g] = excl; cur[g] = excl; }
  if (g == NNODES - 1) off[NNODES] = excl + x;
}

__global__ void scat_k(const int* __restrict__ edges,
                       unsigned* __restrict__ cur, unsigned* __restrict__ rec) {
  const int t = blockIdx.x * 256 + threadIdx.x;
  int4 e = ((const int4*)edges)[t];
#pragma unroll
  for (int h = 0; h < 2; ++h) {
    const int a = h ? e.z : e.x;
    const int b = h ? e.w : e.y;
    rec[atomicAdd(&cur[a], 1u)] = (unsigned)b;
    rec[atomicAdd(&cur[b], 1u)] = (unsigned)a;
  }
}

// ============================================================================
// Last-resort fallback: round-0 atomic-scatter kernel
// ============================================================================

__global__ void init_out(const float* __restrict__ nodes, float* __restrict__ out) {
  int i = blockIdx.x * blockDim.x + threadIdx.x;
  ((float4*)out)[i] = ((const float4*)nodes)[i];
}

__launch_bounds__(256, 2)
__global__ void edge_mlp(const float* __restrict__ nodes,
                         const int* __restrict__ edges,
                         const float* __restrict__ W1,
                         const float* __restrict__ b1,
                         const float* __restrict__ W2,
                         const float* __restrict__ b2,
                         float* __restrict__ out) {
  __shared__ __bf16 w1t[128 * 128];
  __shared__ __bf16 w2t[64 * 128];
  __shared__ __bf16 hid[4][16 * 128];

  const int tid = threadIdx.x;

  for (int it = 0; it < 16; ++it) {
    int q = it * 256 + tid;
    int k = q >> 5;
    int nc = (q & 31) << 2;
    float4 v = ((const float4*)W1)[q];
    float vv[4] = {v.x, v.y, v.z, v.w};
#pragma unroll
    for (int c = 0; c < 4; ++c) {
      int n = nc + c;
      int blk = (k >> 3) ^ (n & 15);
      w1t[n * 128 + blk * 8 + (k & 7)] = f2bf(vv[c]);
    }
  }
  for (int it = 0; it < 8; ++it) {
    int q = it * 256 + tid;
    int k = q >> 4;
    int nc = (q & 15) << 2;
    float4 v = ((const float4*)W2)[q];
    float vv[4] = {v.x, v.y, v.z, v.w};
#pragma unroll
    for (int c = 0; c < 4; ++c) {
      int n = nc + c;
      int blk = (k >> 3) ^ (n & 15);
      w2t[n * 128 + blk * 8 + (k & 7)] = f2bf(vv[c]);
    }
  }
  __syncthreads();

  const int lane = tid & 63;
  const int wave = tid >> 6;
  const int col = lane & 15;
  const int quad = lane >> 4;
  __bf16* myhid = hid[wave];

  float b1v[8], b2v[4];
#pragma unroll
  for (int nt = 0; nt < 8; ++nt) b1v[nt] = b1[nt * 16 + col];
#pragma unroll
  for (int nt = 0; nt < 4; ++nt) b2v[nt] = b2[nt * 16 + col];

  for (int t = 0; t < 8; ++t) {
    const int e0 = blockIdx.x * 512 + wave * 128 + t * 16;
    const int e = e0 + col;
    const int ie = edges[2 * e];
    const int je = edges[2 * e + 1];

    bf16x8 af[4];
#pragma unroll
    for (int kt = 0; kt < 4; ++kt) {
      int k = kt * 32 + quad * 8;
      const float* src = (k < 64) ? (nodes + (long)ie * 64 + k)
                                  : (nodes + (long)je * 64 + (k - 64));
      float4 v0 = ((const float4*)src)[0];
      float4 v1 = ((const float4*)src)[1];
      bf16x8 a;
      a[0] = f2bf(v0.x); a[1] = f2bf(v0.y); a[2] = f2bf(v0.z); a[3] = f2bf(v0.w);
      a[4] = f2bf(v1.x); a[5] = f2bf(v1.y); a[6] = f2bf(v1.z); a[7] = f2bf(v1.w);
      af[kt] = a;
    }

#pragma unroll
    for (int dir = 0; dir < 2; ++dir) {
      f32x4 acc[8];
#pragma unroll
      for (int nt = 0; nt < 8; ++nt) acc[nt] = (f32x4)0.0f;
#pragma unroll
      for (int kt = 0; kt < 4; ++kt) {
        int kblk = kt * 4 + quad;
        if (dir) kblk ^= 8;
#pragma unroll
        for (int nt = 0; nt < 8; ++nt) {
          int n = nt * 16 + col;
          const bf16x8 bf = *(const bf16x8*)&w1t[n * 128 + ((kblk ^ (n & 15)) << 3)];
          acc[nt] = __builtin_amdgcn_mfma_f32_16x16x32_bf16(af[kt], bf, acc[nt], 0, 0, 0);
        }
      }
#pragma unroll
      for (int nt = 0; nt < 8; ++nt) {
        int unit = nt * 16 + col;
#pragma unroll
        for (int r = 0; r < 4; ++r) {
          int m = quad * 4 + r;
          float h = acc[nt][r] + b1v[nt];
          h = h > 0.0f ? h : 0.0f;
          myhid[m * 128 + (((unit >> 3) ^ m) << 3) + (unit & 7)] = f2bf(h);
        }
      }

      f32x4 acc2[4];
#pragma unroll
      for (int nt = 0; nt < 4; ++nt) acc2[nt] = (f32x4)0.0f;
#pragma unroll
      for (int kt = 0; kt < 4; ++kt) {
        int kblk = kt * 4 + quad;
        const bf16x8 ah = *(const bf16x8*)&myhid[col * 128 + ((kblk ^ col) << 3)];
#pragma unroll
        for (int nt = 0; nt < 4; ++nt) {
          int n = nt * 16 + col;
          const bf16x8 bf = *(const bf16x8*)&w2t[n * 128 + ((kblk ^ (n & 15)) << 3)];
          acc2[nt] = __builtin_amdgcn_mfma_f32_16x16x32_bf16(ah, bf, acc2[nt], 0, 0, 0);
        }
      }

#pragma unroll
      for (int r = 0; r < 4; ++r) {
        int em = quad * 4 + r;
        int node = __shfl(dir == 0 ? ie : je, em, 64);
        float* dst = out + (long)node * 64;
#pragma unroll
        for (int nt = 0; nt < 4; ++nt) {
          atomicAdd(dst + nt * 16 + col, acc2[nt][r] + b2v[nt]);
        }
      }
    }
  }
}

// ============================================================================

extern "C" void kernel_launch(void* const* d_in, const int* in_sizes, int n_in,
                              void* d_out, int out_size, void* d_ws, size_t ws_size,
                              hipStream_t stream) {
  const float* nodes = (const float*)d_in[0];
  const int*   edges = (const int*)d_in[1];
  const float* W1    = (const float*)d_in[2];
  const float* b1    = (const float*)d_in[3];
  const float* W2    = (const float*)d_in[4];
  const float* b2    = (const float*)d_in[5];
  float* out = (float*)d_out;

  char* w = (char*)d_ws;
  auto al = [](size_t x) { return (x + 255) & ~(size_t)255; };

  const int CAP = 64;

  // ---- bucket layout ----
  size_t o = 0;
  unsigned* cnt = (unsigned*)(w + o); o = al(o + (size_t)NNODES * 4);
  unsigned* ovn = (unsigned*)(w + o); o = al(o + 256);
  __bf16* wimg  = (__bf16*)(w + o);   o = al(o + (size_t)24576 * 2);
  __bf16* nbf   = (__bf16*)(w + o);   o = al(o + (size_t)NNODES * 64 * 2);
  unsigned* ovf = (unsigned*)(w + o); o = al(o + (size_t)OVCAP * 2 * 4);
  unsigned* rec2 = (unsigned*)(w + o);
  const size_t need_bucket = o + (size_t)NNODES * CAP * 4;

  // ---- CSR layout (reuses cnt/wimg/nbf slots; ovf region repurposed) ----
  size_t c = (size_t)((char*)ovf - w);
  unsigned* off  = (unsigned*)(w + c); c = al(c + ((size_t)NNODES + 1) * 4);
  unsigned* cur  = (unsigned*)(w + c); c = al(c + (size_t)NNODES * 4);
  unsigned* bsum = (unsigned*)(w + c); c = al(c + 128 * 4);
  unsigned* rec  = (unsigned*)(w + c);
  const size_t need_csr = c + (size_t)2 * NEDGES * 4;

  if (d_ws && ws_size >= need_bucket) {
    zero_k<<<391, 256, 0, stream>>>(cnt, ovn);
    build_k<<<3125, 256, 0, stream>>>(nodes, edges, W1, W2, cnt, rec2, ovf, ovn,
                                      wimg, nbf, CAP);
    gnn_k<<<25000, 256, 0, stream>>>(nbf, nodes, cnt, rec2, wimg, b1, b2, out);
    ovf_k<<<104, 256, 0, stream>>>(nodes, W1, b1, W2, b2, ovf, ovn, out);
  } else if (d_ws && ws_size >= need_csr) {
    prep_k<<<3125, 256, 0, stream>>>(nodes, W1, W2, cnt, wimg, nbf);
    hist_k<<<1563, 256, 0, stream>>>(edges, cnt);
    scanA_k<<<98, 1024, 0, stream>>>(cnt, bsum);
    scanB_k<<<98, 1024, 0, stream>>>(cnt, bsum, off, cur);
    scat_k<<<1563, 256, 0, stream>>>(edges, cur, rec);
    gnn_csr_k<<<25000, 256, 0, stream>>>(nbf, nodes, off, rec, wimg, b1, b2, out);
  } else {
    init_out<<<6250, 256, 0, stream>>>(nodes, out);
    edge_mlp<<<3125, 256, 0, stream>>>(nodes, edges, W1, b1, W2, b2, out);
  }
}